// Round 1
// baseline (457.970 us; speedup 1.0000x reference)
//
#include <hip/hip_runtime.h>
#include <cmath>

#define SS 48
#define S3 (SS*SS*SS)      // 110592
#define NB 8
#define CIN 4
#define COUT 4
#define HID 128
#define XT 27              // K^3 taps
#define NP 20              // product paths
#define BATCH 4
#define WOUT (COUT*CIN*NP) // 320

struct Tables {
    int   pid[64];   // [bj*8+bk] -> path index
    float sgn[64];   // [bj*8+bk] -> +-1
};

__device__ __forceinline__ float gelu_tanh(float v) {
    const float c = 0.7978845608028654f;   // sqrt(2/pi)
    float u = c * (v + 0.044715f * v * v * v);
    return 0.5f * v * (1.0f + tanhf(u));
}

// ---------------- Stage 1: masked global pooling -> cond sums (B, NB) -------
__global__ void cond_kernel(const float* __restrict__ x, float* __restrict__ cond) {
    int b = blockIdx.x >> 5;          // 32 blocks per batch sample
    int chunk = blockIdx.x & 31;
    const int per = (CIN * S3) / 32;  // 13824
    int t = threadIdx.x;
    float acc[NB];
#pragma unroll
    for (int n = 0; n < NB; ++n) acc[n] = 0.0f;
    const float* xb = x + (size_t)b * CIN * S3 * NB;
    int end = (chunk + 1) * per;
    for (int idx = chunk * per + t; idx < end; idx += 256) {
        int v = idx % S3;
        int z = v / (SS * SS);
        int rem = v % (SS * SS);
        int y = rem / SS;
        int xx = rem % SS;
        int dx = 2 * xx - 47, dy = 2 * y - 47, dz = 2 * z - 47;
        if (dx * dx + dy * dy + dz * dz <= 2209) {   // 47^2, exact circular mask
            const float4* p4 = (const float4*)(xb + (size_t)idx * NB);
            float4 a = p4[0], c4 = p4[1];
            acc[0] += a.x;  acc[1] += a.y;  acc[2] += a.z;  acc[3] += a.w;
            acc[4] += c4.x; acc[5] += c4.y; acc[6] += c4.z; acc[7] += c4.w;
        }
    }
#pragma unroll
    for (int n = 0; n < NB; ++n)
        for (int off = 32; off; off >>= 1)
            acc[n] += __shfl_down(acc[n], off);
    if ((t & 63) == 0) {
#pragma unroll
        for (int n = 0; n < NB; ++n)
            atomicAdd(&cond[b * NB + n], acc[n]);
    }
}

// ---------------- Stage 2: per-sample kernel network (MLP) ------------------
__global__ void mlp_kernel(const float* __restrict__ cond,
                           const float* __restrict__ w0, const float* __restrict__ b0,
                           const float* __restrict__ w1, const float* __restrict__ b1,
                           const float* __restrict__ w2, const float* __restrict__ b2,
                           float* __restrict__ wout, float inv_norm) {
    int bx = blockIdx.x;
    int b = bx / XT;
    int xx = bx % XT;
    int t = threadIdx.x;
    __shared__ float feat[2 * NB];
    __shared__ float h1[HID];
    __shared__ float h2[HID];
    if (t < 2 * NB) {
        float v = 0.0f;
        if (t < NB) {
            if (t == 1) v = (float)(xx / 9) - 1.0f;
            else if (t == 2) v = (float)((xx / 3) % 3) - 1.0f;
            else if (t == 3) v = (float)(xx % 3) - 1.0f;
        } else {
            v = cond[b * NB + (t - NB)] * inv_norm;
        }
        feat[t] = v;
    }
    __syncthreads();
    float s = b0[t];
#pragma unroll
    for (int k = 0; k < 2 * NB; ++k) s += feat[k] * w0[k * HID + t];
    h1[t] = gelu_tanh(s);
    __syncthreads();
    s = b1[t];
    for (int k = 0; k < HID; ++k) s += h1[k] * w1[k * HID + t];
    h2[t] = gelu_tanh(s);
    __syncthreads();
    float* wo = wout + (size_t)(b * XT + xx) * WOUT;
    for (int j = t; j < WOUT; j += HID) {
        float o = b2[j];
        for (int k = 0; k < HID; ++k) o += h2[k] * w2[k * WOUT + j];
        wo[j] = o;
    }
}

// ---------------- Stage 3: Cayley assembly ----------------------------------
// ker layout: [b][o][tap][i][bj][bk]  (bk fastest)
__global__ void assemble_kernel(const float* __restrict__ w, float* __restrict__ ker,
                                Tables tb) {
    int t = blockIdx.x * 256 + threadIdx.x;
    if (t >= BATCH * COUT * XT * CIN * 64) return;
    int bk  = t & 7;
    int bj  = (t >> 3) & 7;
    int i   = (t >> 6) & 3;
    int tap = (t >> 8) % 27;
    int o   = (t / (27 * 256)) & 3;
    int b   = t / (27 * 256 * 4);
    int jk  = bj * 8 + bk;
    float val = tb.sgn[jk] *
        w[(size_t)(b * XT + tap) * WOUT + o * (CIN * NP) + i * NP + tb.pid[jk]];
    ker[t] = val;
}

// ---------------- Stage 4: grouped conv -------------------------------------
__global__ __launch_bounds__(256)
void conv_kernel(const float* __restrict__ x, const float* __restrict__ ker,
                 const float* __restrict__ bias, float* __restrict__ out) {
    int v = blockIdx.x * 256 + threadIdx.x;   // voxel 0..110591
    int bo = blockIdx.y;                       // b*4 + o
    int b = bo >> 2;
    int o = bo & 3;
    int z = v / (SS * SS);
    int rem = v % (SS * SS);
    int y = rem / SS;
    int xx = rem % SS;
    float acc[NB];
#pragma unroll
    for (int n = 0; n < NB; ++n) acc[n] = 0.0f;
    acc[0] = bias[o];                          // multivector bias at blade 0
    const float* kb = ker + (size_t)bo * (XT * CIN * 64);
    const float* xb = x + (size_t)b * CIN * S3 * NB;
    for (int kz = 0; kz < 3; ++kz) {
        int zz = z + kz - 1;
        if (zz < 0 || zz >= SS) continue;
        for (int ky = 0; ky < 3; ++ky) {
            int yy = y + ky - 1;
            if (yy < 0 || yy >= SS) continue;
            for (int kx = 0; kx < 3; ++kx) {
                int xq = xx + kx - 1;
                if (xq < 0 || xq >= SS) continue;
                const float* kt = kb + ((kz * 3 + ky) * 3 + kx) * (CIN * 64);
                size_t sb = ((size_t)((zz * SS + yy) * SS + xq)) * NB;
#pragma unroll
                for (int i = 0; i < CIN; ++i) {
                    const float4* p4 = (const float4*)(xb + (size_t)i * S3 * NB + sb);
                    float4 a = p4[0], c4 = p4[1];
                    float xv[8] = {a.x, a.y, a.z, a.w, c4.x, c4.y, c4.z, c4.w};
                    const float* ki = kt + i * 64;   // wave-uniform address
#pragma unroll
                    for (int bj = 0; bj < 8; ++bj)
#pragma unroll
                        for (int bk = 0; bk < 8; ++bk)
                            acc[bk] += ki[bj * 8 + bk] * xv[bj];
                }
            }
        }
    }
    float4* po = (float4*)(out + ((size_t)bo * S3 + v) * NB);
    po[0] = make_float4(acc[0], acc[1], acc[2], acc[3]);
    po[1] = make_float4(acc[4], acc[5], acc[6], acc[7]);
}

// ---------------- host ------------------------------------------------------
static inline int pc_host(int v) { return __builtin_popcount(v); }

extern "C" void kernel_launch(void* const* d_in, const int* in_sizes, int n_in,
                              void* d_out, int out_size, void* d_ws, size_t ws_size,
                              hipStream_t stream) {
    const float* x    = (const float*)d_in[0];
    const float* w0   = (const float*)d_in[1];
    const float* b0   = (const float*)d_in[2];
    const float* w1   = (const float*)d_in[3];
    const float* b1   = (const float*)d_in[4];
    const float* w2   = (const float*)d_in[5];
    const float* b2   = (const float*)d_in[6];
    const float* bias = (const float*)d_in[7];
    float* out = (float*)d_out;

    float* ws   = (float*)d_ws;
    float* cond = ws;                 // 32 floats
    float* wbuf = ws + 64;            // 34560 floats (B*27*320)
    float* kerb = ws + 64 + 34560;    // 110592 floats

    // circular-mask voxel count (exact integer arithmetic)
    int cnt = 0;
    for (int z = 0; z < SS; ++z) {
        int dz = 2 * z - 47;
        for (int y = 0; y < SS; ++y) {
            int dy = 2 * y - 47;
            for (int xx = 0; xx < SS; ++xx) {
                int dx = 2 * xx - 47;
                if (dx * dx + dy * dy + dz * dz <= 2209) ++cnt;
            }
        }
    }
    float inv_norm = 1.0f / ((float)cnt * (float)CIN);

    // Cayley sign/path tables
    int pidtab[4][4][4];
    {
        bool ex[4][4][4] = {};
        for (int A = 0; A < 8; ++A)
            for (int B = 0; B < 8; ++B)
                ex[pc_host(A)][pc_host(B)][pc_host(A ^ B)] = true;
        int p = 0;
        for (int gi = 0; gi < 4; ++gi)
            for (int gj = 0; gj < 4; ++gj)
                for (int gk = 0; gk < 4; ++gk)
                    pidtab[gi][gj][gk] = ex[gi][gj][gk] ? p++ : -1;
    }
    static const int blades[8] = {0, 1, 2, 4, 3, 5, 6, 7};  // sorted by (grade, bitmask)
    Tables tb;
    for (int bj = 0; bj < 8; ++bj) {
        for (int bk = 0; bk < 8; ++bk) {
            int bmj = blades[bj], bmk = blades[bk];
            int bma = bmj ^ bmk;            // first-operand bitmask
            int sgn = 1, t = bma >> 1;
            while (t) {
                if (pc_host(t & bmj) & 1) sgn = -sgn;
                t >>= 1;
            }
            tb.sgn[bj * 8 + bk] = (float)sgn;
            tb.pid[bj * 8 + bk] = pidtab[pc_host(bma)][pc_host(bmj)][pc_host(bmk)];
        }
    }

    hipMemsetAsync(cond, 0, 32 * sizeof(float), stream);
    cond_kernel<<<dim3(128), dim3(256), 0, stream>>>(x, cond);
    mlp_kernel<<<dim3(BATCH * XT), dim3(HID), 0, stream>>>(cond, w0, b0, w1, b1, w2, b2,
                                                           wbuf, inv_norm);
    assemble_kernel<<<dim3(432), dim3(256), 0, stream>>>(wbuf, kerb, tb);
    dim3 g(432, 16);
    conv_kernel<<<g, dim3(256), 0, stream>>>(x, kerb, bias, out);
}

// Round 2
// 144.680 us; speedup vs baseline: 3.1654x; 3.1654x over previous
//
#include <hip/hip_runtime.h>
#include <cmath>

#define SS 48
#define S3 110592
#define NB 8
#define CIN 4
#define COUT 4
#define HID 128
#define XT 27
#define NP 20
#define BATCH 4
#define WOUT 320          // COUT*CIN*NP
#define PD 50
#define PD2 2500
#define PD3 125000

typedef __attribute__((ext_vector_type(8))) short short8;
typedef __attribute__((ext_vector_type(4))) float f32x4;

struct Tables {
    int   pid[64];   // [bj*8+bk] -> path index
    float sgn[64];   // [bj*8+bk] -> +-1
};

__device__ __forceinline__ unsigned short bf16_rne(float f) {
    union { float f; unsigned u; } c; c.f = f;
    unsigned r = c.u + 0x7FFF + ((c.u >> 16) & 1);
    return (unsigned short)(r >> 16);
}

__device__ __forceinline__ float gelu_tanh(float v) {
    const float c = 0.7978845608028654f;   // sqrt(2/pi)
    float u = c * (v + 0.044715f * v * v * v);
    return 0.5f * v * (1.0f + tanhf(u));
}

// ---------- Stage 1: pack x -> padded bf16 [b][pz][py][px][c] + masked cond sums
__global__ __launch_bounds__(256)
void pack_cond_kernel(const float* __restrict__ x, unsigned short* __restrict__ xb,
                      float* __restrict__ cond) {
    int b  = blockIdx.y;
    int pv = blockIdx.x * 256 + threadIdx.x;
    __shared__ float sacc[8];
    if (threadIdx.x < 8) sacc[threadIdx.x] = 0.0f;
    __syncthreads();
    float acc[8];
#pragma unroll
    for (int n = 0; n < 8; ++n) acc[n] = 0.0f;
    if (pv < PD3) {
        int zp = pv / PD2, rem = pv % PD2, yp = rem / PD, xp = rem % PD;
        int z = zp - 1, y = yp - 1, xx = xp - 1;
        unsigned short ob[32];
        bool interior = (unsigned)z < 48u && (unsigned)y < 48u && (unsigned)xx < 48u;
        if (interior) {
            int v = (z * 48 + y) * 48 + xx;
            float vals[32];
#pragma unroll
            for (int i = 0; i < 4; ++i) {
                const f32x4* p = (const f32x4*)(x + (((size_t)(b * 4 + i)) * S3 + v) * 8);
                f32x4 a = p[0], c4 = p[1];
                vals[i * 8 + 0] = a[0];  vals[i * 8 + 1] = a[1];
                vals[i * 8 + 2] = a[2];  vals[i * 8 + 3] = a[3];
                vals[i * 8 + 4] = c4[0]; vals[i * 8 + 5] = c4[1];
                vals[i * 8 + 6] = c4[2]; vals[i * 8 + 7] = c4[3];
            }
            int dx = 2 * xx - 47, dy = 2 * y - 47, dz = 2 * z - 47;
            if (dx * dx + dy * dy + dz * dz <= 2209) {
#pragma unroll
                for (int n = 0; n < 8; ++n)
                    acc[n] = vals[n] + vals[8 + n] + vals[16 + n] + vals[24 + n];
            }
#pragma unroll
            for (int k = 0; k < 32; ++k) ob[k] = bf16_rne(vals[k]);
        } else {
#pragma unroll
            for (int k = 0; k < 32; ++k) ob[k] = 0;
        }
        short8* dst = (short8*)(xb + ((size_t)b * PD3 + pv) * 32);
#pragma unroll
        for (int q = 0; q < 4; ++q) {
            short8 s;
#pragma unroll
            for (int e = 0; e < 8; ++e) s[e] = (short)ob[q * 8 + e];
            dst[q] = s;
        }
    }
#pragma unroll
    for (int n = 0; n < 8; ++n) {
        float a = acc[n];
        for (int off = 32; off; off >>= 1) a += __shfl_down(a, off);
        if ((threadIdx.x & 63) == 0) atomicAdd(&sacc[n], a);
    }
    __syncthreads();
    if (threadIdx.x < 8) atomicAdd(&cond[b * 8 + threadIdx.x], sacc[threadIdx.x]);
}

// ---------- Stage 2: per-sample kernel network (MLP) ------------------------
__global__ void mlp_kernel(const float* __restrict__ cond,
                           const float* __restrict__ w0, const float* __restrict__ b0,
                           const float* __restrict__ w1, const float* __restrict__ b1,
                           const float* __restrict__ w2, const float* __restrict__ b2,
                           float* __restrict__ wout, float inv_norm) {
    int bx = blockIdx.x;
    int b = bx / XT;
    int xx = bx % XT;
    int t = threadIdx.x;
    __shared__ float feat[2 * NB];
    __shared__ float h1[HID];
    __shared__ float h2[HID];
    if (t < 2 * NB) {
        float v = 0.0f;
        if (t < NB) {
            if (t == 1) v = (float)(xx / 9) - 1.0f;
            else if (t == 2) v = (float)((xx / 3) % 3) - 1.0f;
            else if (t == 3) v = (float)(xx % 3) - 1.0f;
        } else {
            v = cond[b * NB + (t - NB)] * inv_norm;
        }
        feat[t] = v;
    }
    __syncthreads();
    float s = b0[t];
#pragma unroll
    for (int k = 0; k < 2 * NB; ++k) s += feat[k] * w0[k * HID + t];
    h1[t] = gelu_tanh(s);
    __syncthreads();
    s = b1[t];
    for (int k = 0; k < HID; ++k) s += h1[k] * w1[k * HID + t];
    h2[t] = gelu_tanh(s);
    __syncthreads();
    float* wo = wout + (size_t)(b * XT + xx) * WOUT;
    for (int j = t; j < WOUT; j += HID) {
        float o = b2[j];
        for (int k = 0; k < HID; ++k) o += h2[k] * w2[k * WOUT + j];
        wo[j] = o;
    }
}

// ---------- Stage 3: Cayley assembly -> bf16 Wb[b][t][m=o*8+bk][c=i*8+bj] ---
__global__ void wassemble_kernel(const float* __restrict__ w, unsigned short* __restrict__ wb,
                                 Tables tb) {
    int t = blockIdx.x * 256 + threadIdx.x;      // (b*27+tap)*32 + m
    if (t >= BATCH * XT * 32) return;
    int m = t & 31;
    int bt = t >> 5;                              // b*27 + tap
    int o = m >> 3, bk = m & 7;
    const float* wr = w + (size_t)bt * WOUT + o * (CIN * NP);
    unsigned short ob[32];
#pragma unroll
    for (int c = 0; c < 32; ++c) {
        int i = c >> 3, bj = c & 7, jk = bj * 8 + bk;
        ob[c] = bf16_rne(tb.sgn[jk] * wr[i * NP + tb.pid[jk]]);
    }
    short8* dst = (short8*)(wb + (size_t)t * 32);
#pragma unroll
    for (int q = 0; q < 4; ++q) {
        short8 s;
#pragma unroll
        for (int e = 0; e < 8; ++e) s[e] = (short)ob[q * 8 + e];
        dst[q] = s;
    }
}

// ---------- Stage 4: MFMA grouped conv --------------------------------------
// wave: 32 m x 64 voxels (4 runs of 16 along x); 27 taps x {2 A, 4 B loads, 8 mfma}
__global__ __launch_bounds__(256)
void conv_mfma(const unsigned short* __restrict__ xb, const unsigned short* __restrict__ wb,
               const float* __restrict__ bias, float* __restrict__ out) {
    int b = blockIdx.y;
    int lane = threadIdx.x & 63;
    int wave = threadIdx.x >> 6;
    int col = lane & 15, kl = lane >> 4;
    int R0 = blockIdx.x * 16 + wave * 4;

    size_t ebase[4];
    int vox[4];
#pragma unroll
    for (int r = 0; r < 4; ++r) {
        int R = R0 + r;
        int row = R / 3, xr = R % 3;
        int z = row / 48, y = row % 48, x0 = xr * 16;
        ebase[r] = ((size_t)b * PD3 + (size_t)(z + 1) * PD2 + (y + 1) * PD + (x0 + 1 + col)) * 32
                   + 8 * kl;
        vox[r] = (z * 48 + y) * 48 + x0 + col;
    }
    size_t wbase = (((size_t)b * XT) * 32 + col) * 32 + 8 * kl;

    f32x4 acc[2][4];
#pragma unroll
    for (int mh = 0; mh < 2; ++mh)
#pragma unroll
        for (int r = 0; r < 4; ++r)
#pragma unroll
            for (int e = 0; e < 4; ++e) acc[mh][r][e] = 0.0f;

#pragma unroll
    for (int kz = 0; kz < 3; ++kz)
#pragma unroll
        for (int ky = 0; ky < 3; ++ky)
#pragma unroll
            for (int kx = 0; kx < 3; ++kx) {
                const int tp = (kz * 3 + ky) * 3 + kx;
                const int soff = ((kz - 1) * PD2 + (ky - 1) * PD + (kx - 1)) * 32;
                short8 af0 = *(const short8*)(wb + wbase + (size_t)(tp * 32) * 32);
                short8 af1 = *(const short8*)(wb + wbase + (size_t)(tp * 32 + 16) * 32);
                short8 bfr[4];
#pragma unroll
                for (int r = 0; r < 4; ++r)
                    bfr[r] = *(const short8*)(xb + (ebase[r] + soff));
#pragma unroll
                for (int r = 0; r < 4; ++r) {
                    acc[0][r] = __builtin_amdgcn_mfma_f32_16x16x32_bf16(af0, bfr[r], acc[0][r], 0, 0, 0);
                    acc[1][r] = __builtin_amdgcn_mfma_f32_16x16x32_bf16(af1, bfr[r], acc[1][r], 0, 0, 0);
                }
            }

#pragma unroll
    for (int mh = 0; mh < 2; ++mh) {
        int m0 = kl * 4 + mh * 16;          // first of 4 consecutive m rows
        int o = m0 >> 3, bk0 = m0 & 7;
        float bi = (bk0 == 0) ? bias[o] : 0.0f;
#pragma unroll
        for (int r = 0; r < 4; ++r) {
            f32x4 v = acc[mh][r];
            v[0] += bi;
            *(f32x4*)(out + (((size_t)(b * 4 + o)) * S3 + vox[r]) * 8 + bk0) = v;
        }
    }
}

// ---------------- host ------------------------------------------------------
static inline int pc_host(int v) { return __builtin_popcount(v); }

extern "C" void kernel_launch(void* const* d_in, const int* in_sizes, int n_in,
                              void* d_out, int out_size, void* d_ws, size_t ws_size,
                              hipStream_t stream) {
    const float* x    = (const float*)d_in[0];
    const float* w0   = (const float*)d_in[1];
    const float* b0   = (const float*)d_in[2];
    const float* w1   = (const float*)d_in[3];
    const float* b1   = (const float*)d_in[4];
    const float* w2   = (const float*)d_in[5];
    const float* b2   = (const float*)d_in[6];
    const float* bias = (const float*)d_in[7];
    float* out = (float*)d_out;

    float* ws   = (float*)d_ws;
    float* cond = ws;                           // 32 floats
    float* wbuf = ws + 64;                      // 34560 floats (B*27*320)
    unsigned short* xb  = (unsigned short*)(ws + 64 + 34560);   // padded bf16 x, 32 MB
    unsigned short* wbb = xb + (size_t)BATCH * PD3 * 32;        // bf16 W, 221 KB

    // circular-mask voxel count (exact integer arithmetic)
    int cnt = 0;
    for (int z = 0; z < SS; ++z) {
        int dz = 2 * z - 47;
        for (int y = 0; y < SS; ++y) {
            int dy = 2 * y - 47;
            for (int xx = 0; xx < SS; ++xx) {
                int dx = 2 * xx - 47;
                if (dx * dx + dy * dy + dz * dz <= 2209) ++cnt;
            }
        }
    }
    float inv_norm = 1.0f / ((float)cnt * (float)CIN);

    // Cayley sign/path tables
    int pidtab[4][4][4];
    {
        bool ex[4][4][4] = {};
        for (int A = 0; A < 8; ++A)
            for (int B = 0; B < 8; ++B)
                ex[pc_host(A)][pc_host(B)][pc_host(A ^ B)] = true;
        int p = 0;
        for (int gi = 0; gi < 4; ++gi)
            for (int gj = 0; gj < 4; ++gj)
                for (int gk = 0; gk < 4; ++gk)
                    pidtab[gi][gj][gk] = ex[gi][gj][gk] ? p++ : -1;
    }
    static const int blades[8] = {0, 1, 2, 4, 3, 5, 6, 7};  // sorted by (grade, bitmask)
    Tables tb;
    for (int bj = 0; bj < 8; ++bj) {
        for (int bk = 0; bk < 8; ++bk) {
            int bmj = blades[bj], bmk = blades[bk];
            int bma = bmj ^ bmk;
            int sgn = 1, t = bma >> 1;
            while (t) {
                if (pc_host(t & bmj) & 1) sgn = -sgn;
                t >>= 1;
            }
            tb.sgn[bj * 8 + bk] = (float)sgn;
            tb.pid[bj * 8 + bk] = pidtab[pc_host(bma)][pc_host(bmj)][pc_host(bmk)];
        }
    }

    hipMemsetAsync(cond, 0, 32 * sizeof(float), stream);
    pack_cond_kernel<<<dim3(489, BATCH), dim3(256), 0, stream>>>(x, xb, cond);
    mlp_kernel<<<dim3(BATCH * XT), dim3(HID), 0, stream>>>(cond, w0, b0, w1, b1, w2, b2,
                                                           wbuf, inv_norm);
    wassemble_kernel<<<dim3(14), dim3(256), 0, stream>>>(wbuf, wbb, tb);
    conv_mfma<<<dim3(432, BATCH), dim3(256), 0, stream>>>(xb, wbb, bias, out);
}

// Round 3
// 111.733 us; speedup vs baseline: 4.0988x; 1.2949x over previous
//
#include <hip/hip_runtime.h>
#include <cmath>

#define SS 48
#define S3 110592
#define NB 8
#define CIN 4
#define COUT 4
#define HID 128
#define XT 27
#define NP 20
#define BATCH 4
#define WOUT 320          // COUT*CIN*NP
#define PD 50
#define PD2 2500
#define PD3 125000

// conv tiling
#define HV 600            // 10*10*6 halo voxels
#define LSTR 40           // shorts per halo voxel (80 B padded row)

typedef __attribute__((ext_vector_type(8))) short short8;
typedef __attribute__((ext_vector_type(4))) float f32x4;

struct Tables {
    int   pid[64];   // [bj*8+bk] -> path index
    float sgn[64];   // [bj*8+bk] -> +-1
};

__device__ __forceinline__ unsigned short bf16_rne(float f) {
    union { float f; unsigned u; } c; c.f = f;
    unsigned r = c.u + 0x7FFF + ((c.u >> 16) & 1);
    return (unsigned short)(r >> 16);
}

__device__ __forceinline__ float gelu_tanh(float v) {
    const float c = 0.7978845608028654f;   // sqrt(2/pi)
    float u = c * (v + 0.044715f * v * v * v);
    return 0.5f * v * (1.0f + tanhf(u));
}

// ---------- Stage 1: pack x -> padded bf16 [b][pz][py][px][c] + masked cond sums
__global__ __launch_bounds__(256)
void pack_cond_kernel(const float* __restrict__ x, unsigned short* __restrict__ xb,
                      float* __restrict__ cond) {
    int b  = blockIdx.y;
    int pv = blockIdx.x * 256 + threadIdx.x;
    __shared__ float sacc[8];
    if (threadIdx.x < 8) sacc[threadIdx.x] = 0.0f;
    __syncthreads();
    float acc[8];
#pragma unroll
    for (int n = 0; n < 8; ++n) acc[n] = 0.0f;
    if (pv < PD3) {
        int zp = pv / PD2, rem = pv % PD2, yp = rem / PD, xp = rem % PD;
        int z = zp - 1, y = yp - 1, xx = xp - 1;
        unsigned short ob[32];
        bool interior = (unsigned)z < 48u && (unsigned)y < 48u && (unsigned)xx < 48u;
        if (interior) {
            int v = (z * 48 + y) * 48 + xx;
            float vals[32];
#pragma unroll
            for (int i = 0; i < 4; ++i) {
                const f32x4* p = (const f32x4*)(x + (((size_t)(b * 4 + i)) * S3 + v) * 8);
                f32x4 a = p[0], c4 = p[1];
                vals[i * 8 + 0] = a[0];  vals[i * 8 + 1] = a[1];
                vals[i * 8 + 2] = a[2];  vals[i * 8 + 3] = a[3];
                vals[i * 8 + 4] = c4[0]; vals[i * 8 + 5] = c4[1];
                vals[i * 8 + 6] = c4[2]; vals[i * 8 + 7] = c4[3];
            }
            int dx = 2 * xx - 47, dy = 2 * y - 47, dz = 2 * z - 47;
            if (dx * dx + dy * dy + dz * dz <= 2209) {
#pragma unroll
                for (int n = 0; n < 8; ++n)
                    acc[n] = vals[n] + vals[8 + n] + vals[16 + n] + vals[24 + n];
            }
#pragma unroll
            for (int k = 0; k < 32; ++k) ob[k] = bf16_rne(vals[k]);
        } else {
#pragma unroll
            for (int k = 0; k < 32; ++k) ob[k] = 0;
        }
        short8* dst = (short8*)(xb + ((size_t)b * PD3 + pv) * 32);
#pragma unroll
        for (int q = 0; q < 4; ++q) {
            short8 s;
#pragma unroll
            for (int e = 0; e < 8; ++e) s[e] = (short)ob[q * 8 + e];
            dst[q] = s;
        }
    }
#pragma unroll
    for (int n = 0; n < 8; ++n) {
        float a = acc[n];
        for (int off = 32; off; off >>= 1) a += __shfl_down(a, off);
        if ((threadIdx.x & 63) == 0) atomicAdd(&sacc[n], a);
    }
    __syncthreads();
    if (threadIdx.x < 8) atomicAdd(&cond[b * 8 + threadIdx.x], sacc[threadIdx.x]);
}

// ---------- Stage 2: per-sample kernel network (MLP) ------------------------
__global__ void mlp_kernel(const float* __restrict__ cond,
                           const float* __restrict__ w0, const float* __restrict__ b0,
                           const float* __restrict__ w1, const float* __restrict__ b1,
                           const float* __restrict__ w2, const float* __restrict__ b2,
                           float* __restrict__ wout, float inv_norm) {
    int bx = blockIdx.x;
    int b = bx / XT;
    int xx = bx % XT;
    int t = threadIdx.x;
    __shared__ float feat[2 * NB];
    __shared__ float h1[HID];
    __shared__ float h2[HID];
    if (t < 2 * NB) {
        float v = 0.0f;
        if (t < NB) {
            if (t == 1) v = (float)(xx / 9) - 1.0f;
            else if (t == 2) v = (float)((xx / 3) % 3) - 1.0f;
            else if (t == 3) v = (float)(xx % 3) - 1.0f;
        } else {
            v = cond[b * NB + (t - NB)] * inv_norm;
        }
        feat[t] = v;
    }
    __syncthreads();
    float s = b0[t];
#pragma unroll
    for (int k = 0; k < 2 * NB; ++k) s += feat[k] * w0[k * HID + t];
    h1[t] = gelu_tanh(s);
    __syncthreads();
    s = b1[t];
    for (int k = 0; k < HID; ++k) s += h1[k] * w1[k * HID + t];
    h2[t] = gelu_tanh(s);
    __syncthreads();
    float* wo = wout + (size_t)(b * XT + xx) * WOUT;
    for (int j = t; j < WOUT; j += HID) {
        float o = b2[j];
        for (int k = 0; k < HID; ++k) o += h2[k] * w2[k * WOUT + j];
        wo[j] = o;
    }
}

// ---------- Stage 3: Cayley assembly -> bf16 Wb[b][t][m=o*8+bk][c=i*8+bj] ---
__global__ void wassemble_kernel(const float* __restrict__ w, unsigned short* __restrict__ wb,
                                 Tables tb) {
    int t = blockIdx.x * 256 + threadIdx.x;      // (b*27+tap)*32 + m
    if (t >= BATCH * XT * 32) return;
    int m = t & 31;
    int bt = t >> 5;                              // b*27 + tap
    int o = m >> 3, bk = m & 7;
    const float* wr = w + (size_t)bt * WOUT + o * (CIN * NP);
    unsigned short ob[32];
#pragma unroll
    for (int c = 0; c < 32; ++c) {
        int i = c >> 3, bj = c & 7, jk = bj * 8 + bk;
        ob[c] = bf16_rne(tb.sgn[jk] * wr[i * NP + tb.pid[jk]]);
    }
    short8* dst = (short8*)(wb + (size_t)t * 32);
#pragma unroll
    for (int q = 0; q < 4; ++q) {
        short8 s;
#pragma unroll
        for (int e = 0; e < 8; ++e) s[e] = (short)ob[q * 8 + e];
        dst[q] = s;
    }
}

// ---------- Stage 4: MFMA grouped conv, LDS-staged x-tile -------------------
// block: 8x8x4 output tile, 4 waves (one z-slice each, 64 voxels as 4 frags of 8x2)
// halo 10x10x6 staged once; inner loop = ds_read + MFMA only (W from L1).
__global__ __launch_bounds__(256, 3)
void conv_lds(const unsigned short* __restrict__ xb, const unsigned short* __restrict__ wb,
              const float* __restrict__ bias, float* __restrict__ out) {
    __shared__ __align__(16) short lds[HV * LSTR];   // 48000 B
    int b  = blockIdx.y;
    int bx = blockIdx.x;
    int tx = bx % 6, ty = (bx / 6) % 6, tz = bx / 36;
    int X0 = tx * 8, Y0 = ty * 8, Z0 = tz * 4;       // halo origin in padded coords
    int tid = threadIdx.x;

    const unsigned short* xbb = xb + (size_t)b * PD3 * 32;
    for (int c = tid; c < HV * 4; c += 256) {
        int h = c >> 2, sl = c & 3;
        int hz = h / 100;
        int rem = h % 100;
        int hy = rem / 10, hx = rem % 10;
        short8 v = *(const short8*)(xbb +
            ((size_t)(Z0 + hz) * PD2 + (size_t)(Y0 + hy) * PD + (X0 + hx)) * 32 + sl * 8);
        *(short8*)(&lds[h * LSTR + sl * 8]) = v;
    }
    __syncthreads();

    int lane = tid & 63, wave = tid >> 6;
    int col = lane & 15, kl = lane >> 4;
    const short* lbase = &lds[(wave * 100 + (col >> 3) * 10 + (col & 7)) * LSTR + kl * 8];
    size_t wbase = (((size_t)b * XT) * 32 + col) * 32 + kl * 8;

    f32x4 acc[2][4];
#pragma unroll
    for (int mh = 0; mh < 2; ++mh)
#pragma unroll
        for (int r = 0; r < 4; ++r)
#pragma unroll
            for (int e = 0; e < 4; ++e) acc[mh][r][e] = 0.0f;

#pragma unroll
    for (int kz = 0; kz < 3; ++kz)
#pragma unroll
        for (int ky = 0; ky < 3; ++ky)
#pragma unroll
            for (int kx = 0; kx < 3; ++kx) {
                const int tp = (kz * 3 + ky) * 3 + kx;
                short8 af0 = *(const short8*)(wb + wbase + (size_t)(tp * 32) * 32);
                short8 af1 = *(const short8*)(wb + wbase + (size_t)(tp * 32 + 16) * 32);
                const int toff = (kz * 100 + ky * 10 + kx) * LSTR;
#pragma unroll
                for (int r = 0; r < 4; ++r) {
                    short8 bf = *(const short8*)(lbase + toff + r * (20 * LSTR));
                    acc[0][r] = __builtin_amdgcn_mfma_f32_16x16x32_bf16(af0, bf, acc[0][r], 0, 0, 0);
                    acc[1][r] = __builtin_amdgcn_mfma_f32_16x16x32_bf16(af1, bf, acc[1][r], 0, 0, 0);
                }
            }

    int xc = X0 + (col & 7);
    int z  = Z0 + wave;
#pragma unroll
    for (int mh = 0; mh < 2; ++mh) {
        int m0 = kl * 4 + mh * 16;
        int o = m0 >> 3, bk0 = m0 & 7;
        float bi = (bk0 == 0) ? bias[o] : 0.0f;
#pragma unroll
        for (int r = 0; r < 4; ++r) {
            int y = Y0 + (col >> 3) + 2 * r;
            int vox = (z * 48 + y) * 48 + xc;
            f32x4 v = acc[mh][r];
            v[0] += bi;
            *(f32x4*)(out + (((size_t)(b * 4 + o)) * S3 + vox) * 8 + bk0) = v;
        }
    }
}

// ---------------- host ------------------------------------------------------
static inline int pc_host(int v) { return __builtin_popcount(v); }

extern "C" void kernel_launch(void* const* d_in, const int* in_sizes, int n_in,
                              void* d_out, int out_size, void* d_ws, size_t ws_size,
                              hipStream_t stream) {
    const float* x    = (const float*)d_in[0];
    const float* w0   = (const float*)d_in[1];
    const float* b0   = (const float*)d_in[2];
    const float* w1   = (const float*)d_in[3];
    const float* b1   = (const float*)d_in[4];
    const float* w2   = (const float*)d_in[5];
    const float* b2   = (const float*)d_in[6];
    const float* bias = (const float*)d_in[7];
    float* out = (float*)d_out;

    float* ws   = (float*)d_ws;
    float* cond = ws;                           // 32 floats
    float* wbuf = ws + 64;                      // 34560 floats (B*27*320)
    unsigned short* xb  = (unsigned short*)(ws + 64 + 34560);   // padded bf16 x, 32 MB
    unsigned short* wbb = xb + (size_t)BATCH * PD3 * 32;        // bf16 W, 221 KB

    // circular-mask voxel count (exact integer arithmetic)
    int cnt = 0;
    for (int z = 0; z < SS; ++z) {
        int dz = 2 * z - 47;
        for (int y = 0; y < SS; ++y) {
            int dy = 2 * y - 47;
            for (int xx = 0; xx < SS; ++xx) {
                int dx = 2 * xx - 47;
                if (dx * dx + dy * dy + dz * dz <= 2209) ++cnt;
            }
        }
    }
    float inv_norm = 1.0f / ((float)cnt * (float)CIN);

    // Cayley sign/path tables
    int pidtab[4][4][4];
    {
        bool ex[4][4][4] = {};
        for (int A = 0; A < 8; ++A)
            for (int B = 0; B < 8; ++B)
                ex[pc_host(A)][pc_host(B)][pc_host(A ^ B)] = true;
        int p = 0;
        for (int gi = 0; gi < 4; ++gi)
            for (int gj = 0; gj < 4; ++gj)
                for (int gk = 0; gk < 4; ++gk)
                    pidtab[gi][gj][gk] = ex[gi][gj][gk] ? p++ : -1;
    }
    static const int blades[8] = {0, 1, 2, 4, 3, 5, 6, 7};  // sorted by (grade, bitmask)
    Tables tb;
    for (int bj = 0; bj < 8; ++bj) {
        for (int bk = 0; bk < 8; ++bk) {
            int bmj = blades[bj], bmk = blades[bk];
            int bma = bmj ^ bmk;
            int sgn = 1, t = bma >> 1;
            while (t) {
                if (pc_host(t & bmj) & 1) sgn = -sgn;
                t >>= 1;
            }
            tb.sgn[bj * 8 + bk] = (float)sgn;
            tb.pid[bj * 8 + bk] = pidtab[pc_host(bma)][pc_host(bmj)][pc_host(bmk)];
        }
    }

    hipMemsetAsync(cond, 0, 32 * sizeof(float), stream);
    pack_cond_kernel<<<dim3(489, BATCH), dim3(256), 0, stream>>>(x, xb, cond);
    mlp_kernel<<<dim3(BATCH * XT), dim3(HID), 0, stream>>>(cond, w0, b0, w1, b1, w2, b2,
                                                           wbuf, inv_norm);
    wassemble_kernel<<<dim3(14), dim3(256), 0, stream>>>(wbuf, wbb, tb);
    conv_lds<<<dim3(432, BATCH), dim3(256), 0, stream>>>(xb, wbb, bias, out);
}